// Round 5
// baseline (99.429 us; speedup 1.0000x reference)
//
#include <hip/hip_runtime.h>
#include <hip/hip_fp16.h>

#define D_  160
#define H_  192
#define W_  224
#define HW_ (H_ * W_)           // 43008
#define N_  (D_ * H_ * W_)      // 6881280
#define INV729 (1.0f / 729.0f)
#define HSEG 16
#define NSEG (H_ / HSEG)        // 12
#define NSTEP (HSEG + 9)        // 25

// ---------------------------------------------------------------------------
__global__ void k_init(double* acc) { *acc = 0.0; }

// ---------------------------------------------------------------------------
// Fused W+H box-sum, 2 w-points per thread, fp16-packed H-ring, fp16 output.
// Block = 128 threads, one (d, h-segment). Per step: stage one raw I,J row
// (232 floats each, zero halos) via float4 double-buffered LDS; each compute
// thread reads its 10-float window as float2s (8B-aligned -> ds_read2_b64),
// computes 5 W-sums for 2 outputs with sliding reuse, slides the H-sum with a
// statically-indexed mod-9 __half2 ring, emits packed fp16 pairs.
__global__ __launch_bounds__(128) void k_passWH(const float* __restrict__ pred,
                                                const float* __restrict__ targ,
                                                __half2* __restrict__ out2) {
    __shared__ __attribute__((aligned(16))) float bI[2][232];
    __shared__ __attribute__((aligned(16))) float bJ[2][232];
    const int d  = blockIdx.x;
    const int h0 = blockIdx.y * HSEG;
    const int t  = threadIdx.x;
    const long dbase = (long)d * HW_;

    // staging role: t<116 -> array sa (0=I=targ,1=J=pred), chunk sc (0..57)
    // chunk c covers LDS slots [4c,4c+3] = w elements [4c-4, 4c-1]
    const bool stg = (t < 116);
    const int  sa  = (t >= 58) ? 1 : 0;
    const int  sc  = sa ? (t - 58) : t;
    const bool interior = (sc >= 1) && (sc <= 56);   // chunks 0,57 = zero halo
    const float* src = sa ? pred : targ;
    const long srcoff = dbase + (long)(4 * sc - 4);

    // compute role: t<112, owns w = {2t, 2t+1}
    const bool cmp = (t < 112);
    const int  l   = t;

    __half2 q[5][9];
    #pragma unroll
    for (int c = 0; c < 5; ++c)
        #pragma unroll
        for (int k = 0; k < 9; ++k) q[c][k] = __floats2half2_rn(0.f, 0.f);
    float S0[5] = {0,0,0,0,0}, S1[5] = {0,0,0,0,0};

    // prologue prefetch: row h0-5
    float4 pf = make_float4(0.f, 0.f, 0.f, 0.f);
    {
        const int hh = h0 - 5;
        if (stg && interior && hh >= 0)
            pf = *(const float4*)(src + srcoff + (long)hh * W_);
    }

    #pragma unroll
    for (int k = 0; k < NSTEP; ++k) {
        const int cur = k & 1;
        if (stg) {
            float* dst = (sa ? bJ[cur] : bI[cur]) + 4 * sc;
            *(float4*)dst = pf;
        }
        // prefetch next row (hidden under this step's compute)
        pf = make_float4(0.f, 0.f, 0.f, 0.f);
        {
            const int hh = h0 - 4 + k;
            if (stg && interior && (k + 1 < NSTEP) && hh >= 0 && hh < H_)
                pf = *(const float4*)(src + srcoff + (long)hh * W_);
        }
        __syncthreads();
        // hazard: reads of buf[cur] (this step, pre-barrier(k+1)) precede the
        // next write to buf[cur] (step k+2, post-barrier(k+1)). OK.

        if (cmp) {
            // window: w elements 2l-4 .. 2l+5 = slots 2l .. 2l+9 (8B aligned)
            float a[10], b[10];
            #pragma unroll
            for (int m = 0; m < 5; ++m) {
                const float2 va = *(const float2*)&bI[cur][2 * l + 2 * m];
                const float2 vb = *(const float2*)&bJ[cur][2 * l + 2 * m];
                a[2*m] = va.x; a[2*m+1] = va.y;
                b[2*m] = vb.x; b[2*m+1] = vb.y;
            }
            float sI = 0.f, sJ = 0.f, sII = 0.f, sJJ = 0.f, sIJ = 0.f;
            #pragma unroll
            for (int kk = 0; kk < 9; ++kk) {
                sI  += a[kk];          sJ  += b[kk];
                sII += a[kk] * a[kk];  sJJ += b[kk] * b[kk];
                sIJ += a[kk] * b[kk];
            }
            float w0[5], w1[5];
            w0[0] = sI;  w1[0] = sI  + a[9] - a[0];
            w0[1] = sJ;  w1[1] = sJ  + b[9] - b[0];
            w0[2] = sII; w1[2] = sII + a[9]*a[9] - a[0]*a[0];
            w0[3] = sJJ; w1[3] = sJJ + b[9]*b[9] - b[0]*b[0];
            w0[4] = sIJ; w1[4] = sIJ + a[9]*b[9] - a[0]*b[0];

            const int p = k % 9;      // compile-time (full unroll)
            #pragma unroll
            for (int c = 0; c < 5; ++c) {
                const __half2 nq = __floats2half2_rn(w0[c], w1[c]);
                const float2  nf = __half22float2(nq);   // exact added values
                const float2  of = __half22float2(q[c][p]);
                S0[c] += nf.x - of.x;
                S1[c] += nf.y - of.y;
                q[c][p] = nq;
            }
            if (k >= 9) {
                const long o2 = (dbase + (long)(h0 + k - 9) * W_) / 2 + l;
                #pragma unroll
                for (int c = 0; c < 5; ++c)
                    out2[(long)c * (N_ / 2) + o2] = __floats2half2_rn(S0[c], S1[c]);
            }
        }
    }
}

// ---------------------------------------------------------------------------
// D-axis 9-tap sliding sum + cc + reduction (R2 structure, fp16 input).
// grid = (HW/256, 8 segments of 20 d-outputs). Read-only on buf.
__global__ __launch_bounds__(256) void k_passD(const __half* __restrict__ buf,
                                               double* __restrict__ acc) {
    const int DSEG = D_ / 8;                // 20
    const int p  = blockIdx.x * blockDim.x + threadIdx.x;   // < HW_
    const int d0 = blockIdx.y * DSEG;
    const __half* base = buf + p;

    float q[5][9], S[5];
    #pragma unroll
    for (int c = 0; c < 5; ++c) {
        S[c] = 0.f;
        #pragma unroll
        for (int k = 0; k < 9; ++k) {
            const int dd = d0 - 5 + k;      // d0+3 <= 143 < 160
            const float v = (dd >= 0) ? __half2float(base[(long)c * N_ + (long)dd * HW_]) : 0.f;
            q[c][k] = v;
            S[c] += v;
        }
    }

    float myacc = 0.f;
    #pragma unroll 2
    for (int d = d0; d < d0 + DSEG; ++d) {
        float nv[5];
        #pragma unroll
        for (int c = 0; c < 5; ++c) {
            nv[c] = (d + 4 < D_) ? __half2float(base[(long)c * N_ + (long)(d + 4) * HW_]) : 0.f;
            S[c] += nv[c] - q[c][0];
            #pragma unroll
            for (int k = 0; k < 8; ++k) q[c][k] = q[c][k + 1];
            q[c][8] = nv[c];
        }
        const float mu1 = S[0] * INV729;
        const float mu2 = S[1] * INV729;
        const float s1  = S[2] * INV729 - mu1 * mu1;
        const float s2  = S[3] * INV729 - mu2 * mu2;
        const float s12 = S[4] * INV729 - mu1 * mu2;
        const float den = fmaxf(s1 * s2, 1.1920929e-7f);   // finfo(f32).eps
        myacc += (s12 * s12) / den;
    }

    __shared__ float red[256];
    red[threadIdx.x] = myacc;
    __syncthreads();
    #pragma unroll
    for (int s = 128; s > 0; s >>= 1) {
        if (threadIdx.x < s) red[threadIdx.x] += red[threadIdx.x + s];
        __syncthreads();
    }
    if (threadIdx.x == 0) atomicAdd(acc, (double)red[0]);
}

// ---------------------------------------------------------------------------
__global__ void k_fin(const double* __restrict__ acc, float* __restrict__ out) {
    out[0] = (float)(-(*acc) / (double)N_);
}

// ---------------------------------------------------------------------------
extern "C" void kernel_launch(void* const* d_in, const int* in_sizes, int n_in,
                              void* d_out, int out_size, void* d_ws, size_t ws_size,
                              hipStream_t stream) {
    const float* pred = (const float*)d_in[0];
    const float* targ = (const float*)d_in[1];

    __half2* buf2 = (__half2*)d_ws;                               // 5*N halves
    const __half* buf = (const __half*)d_ws;
    double* acc = (double*)((char*)d_ws + (size_t)5 * N_ * 2);    // 8B aligned
    float*  out = (float*)d_out;

    k_init<<<1, 1, 0, stream>>>(acc);
    dim3 g1(D_, NSEG);          // 160 x 12
    k_passWH<<<g1, 128, 0, stream>>>(pred, targ, buf2);
    dim3 g3(HW_ / 256, 8);      // 168 x 8
    k_passD<<<g3, 256, 0, stream>>>(buf, acc);
    k_fin<<<1, 1, 0, stream>>>(acc, out);
}

// Round 6
// 82.393 us; speedup vs baseline: 1.2068x; 1.2068x over previous
//
#include <hip/hip_runtime.h>
#include <hip/hip_fp16.h>

#define D_  160
#define H_  192
#define W_  224
#define HW_ (H_ * W_)           // 43008
#define N_  (D_ * H_ * W_)      // 6881280
#define INV729 (1.0f / 729.0f)
#define HSEG 8
#define NSEG (H_ / HSEG)        // 24
#define NSTEP (HSEG + 9)        // 17

// Intermediate layout: [d][h][w] x uint4 (16B/point): halves (c0,c1),(c2,c3),(c4,pad),pad

// ---------------------------------------------------------------------------
__global__ void k_init(double* acc) { *acc = 0.0; }

__device__ __forceinline__ unsigned pack2(float a, float b) {
    const __half2 h = __floats2half2_rn(a, b);
    return *(const unsigned*)&h;
}

// ---------------------------------------------------------------------------
// Fused W+H box-sum, 2 w-points/thread, fp16 H-ring, channel-interleaved out.
__global__ __launch_bounds__(128) void k_passWH(const float* __restrict__ pred,
                                                const float* __restrict__ targ,
                                                uint4* __restrict__ out4) {
    __shared__ __attribute__((aligned(16))) float bI[2][232];
    __shared__ __attribute__((aligned(16))) float bJ[2][232];
    const int d  = blockIdx.x;
    const int h0 = blockIdx.y * HSEG;
    const int t  = threadIdx.x;
    const long dbase = (long)d * HW_;

    // staging role: t<116 -> array sa (0=I=targ,1=J=pred), chunk sc (0..57)
    const bool stg = (t < 116);
    const int  sa  = (t >= 58) ? 1 : 0;
    const int  sc  = sa ? (t - 58) : t;
    const bool interior = (sc >= 1) && (sc <= 56);   // chunks 0,57 = zero halo
    const float* src = sa ? pred : targ;
    const long srcoff = dbase + (long)(4 * sc - 4);

    const bool cmp = (t < 112);      // owns w = {2t, 2t+1}
    const int  l   = t;

    __half2 q[5][9];
    #pragma unroll
    for (int c = 0; c < 5; ++c)
        #pragma unroll
        for (int k = 0; k < 9; ++k) q[c][k] = __floats2half2_rn(0.f, 0.f);
    float S0[5] = {0,0,0,0,0}, S1[5] = {0,0,0,0,0};

    float4 pf = make_float4(0.f, 0.f, 0.f, 0.f);
    {
        const int hh = h0 - 5;
        if (stg && interior && hh >= 0)
            pf = *(const float4*)(src + srcoff + (long)hh * W_);
    }

    #pragma unroll
    for (int k = 0; k < NSTEP; ++k) {
        const int cur = k & 1;
        if (stg) {
            float* dst = (sa ? bJ[cur] : bI[cur]) + 4 * sc;
            *(float4*)dst = pf;
        }
        pf = make_float4(0.f, 0.f, 0.f, 0.f);
        {
            const int hh = h0 - 4 + k;
            if (stg && interior && (k + 1 < NSTEP) && hh >= 0 && hh < H_)
                pf = *(const float4*)(src + srcoff + (long)hh * W_);
        }
        __syncthreads();
        // hazard: reads of buf[cur] precede barrier(k+1); next write to
        // buf[cur] is in step k+2 after barrier(k+1). OK.

        if (cmp) {
            float a[10], b[10];
            #pragma unroll
            for (int m = 0; m < 5; ++m) {
                const float2 va = *(const float2*)&bI[cur][2 * l + 2 * m];
                const float2 vb = *(const float2*)&bJ[cur][2 * l + 2 * m];
                a[2*m] = va.x; a[2*m+1] = va.y;
                b[2*m] = vb.x; b[2*m+1] = vb.y;
            }
            float sI = 0.f, sJ = 0.f, sII = 0.f, sJJ = 0.f, sIJ = 0.f;
            #pragma unroll
            for (int kk = 0; kk < 9; ++kk) {
                sI  += a[kk];          sJ  += b[kk];
                sII += a[kk] * a[kk];  sJJ += b[kk] * b[kk];
                sIJ += a[kk] * b[kk];
            }
            float w0[5], w1[5];
            w0[0] = sI;  w1[0] = sI  + a[9] - a[0];
            w0[1] = sJ;  w1[1] = sJ  + b[9] - b[0];
            w0[2] = sII; w1[2] = sII + a[9]*a[9] - a[0]*a[0];
            w0[3] = sJJ; w1[3] = sJJ + b[9]*b[9] - b[0]*b[0];
            w0[4] = sIJ; w1[4] = sIJ + a[9]*b[9] - a[0]*b[0];

            const int p = k % 9;      // compile-time
            #pragma unroll
            for (int c = 0; c < 5; ++c) {
                const __half2 nq = __floats2half2_rn(w0[c], w1[c]);
                const float2  nf = __half22float2(nq);
                const float2  of = __half22float2(q[c][p]);
                S0[c] += nf.x - of.x;
                S1[c] += nf.y - of.y;
                q[c][p] = nq;
            }
            if (k >= 9) {
                const long idx = dbase + (long)(h0 + k - 9) * W_ + 2 * l;
                uint4 o0, o1;
                o0.x = pack2(S0[0], S0[1]); o0.y = pack2(S0[2], S0[3]);
                o0.z = pack2(S0[4], 0.f);   o0.w = 0u;
                o1.x = pack2(S1[0], S1[1]); o1.y = pack2(S1[2], S1[3]);
                o1.z = pack2(S1[4], 0.f);   o1.w = 0u;
                out4[idx]     = o0;
                out4[idx + 1] = o1;
            }
        }
    }
}

// ---------------------------------------------------------------------------
// D-axis 9-tap sliding sum + cc + reduction. One uint4 load per point per
// step (channel-interleaved). R2-proven loop structure.
__global__ __launch_bounds__(256) void k_passD(const uint4* __restrict__ buf,
                                               double* __restrict__ acc) {
    const int DSEG = D_ / 8;                // 20
    const int p  = blockIdx.x * blockDim.x + threadIdx.x;   // < HW_
    const int d0 = blockIdx.y * DSEG;
    const uint4* base = buf + p;

    float q[5][9], S[5];
    #pragma unroll
    for (int c = 0; c < 5; ++c) S[c] = 0.f;

    #pragma unroll
    for (int k = 0; k < 9; ++k) {
        const int dd = d0 - 5 + k;          // d0+3 <= 143 < 160
        uint4 v = make_uint4(0u, 0u, 0u, 0u);
        if (dd >= 0) v = base[(long)dd * HW_];
        const float2 f01 = __half22float2(*(const __half2*)&v.x);
        const float2 f23 = __half22float2(*(const __half2*)&v.y);
        const float2 f4x = __half22float2(*(const __half2*)&v.z);
        q[0][k] = f01.x; S[0] += f01.x;
        q[1][k] = f01.y; S[1] += f01.y;
        q[2][k] = f23.x; S[2] += f23.x;
        q[3][k] = f23.y; S[3] += f23.y;
        q[4][k] = f4x.x; S[4] += f4x.x;
    }

    float myacc = 0.f;
    #pragma unroll 2
    for (int d = d0; d < d0 + DSEG; ++d) {
        uint4 v = make_uint4(0u, 0u, 0u, 0u);
        if (d + 4 < D_) v = base[(long)(d + 4) * HW_];
        const float2 f01 = __half22float2(*(const __half2*)&v.x);
        const float2 f23 = __half22float2(*(const __half2*)&v.y);
        const float2 f4x = __half22float2(*(const __half2*)&v.z);
        float nv[5] = {f01.x, f01.y, f23.x, f23.y, f4x.x};
        #pragma unroll
        for (int c = 0; c < 5; ++c) {
            S[c] += nv[c] - q[c][0];
            #pragma unroll
            for (int k = 0; k < 8; ++k) q[c][k] = q[c][k + 1];
            q[c][8] = nv[c];
        }
        const float mu1 = S[0] * INV729;
        const float mu2 = S[1] * INV729;
        const float s1  = S[2] * INV729 - mu1 * mu1;
        const float s2  = S[3] * INV729 - mu2 * mu2;
        const float s12 = S[4] * INV729 - mu1 * mu2;
        const float den = fmaxf(s1 * s2, 1.1920929e-7f);   // finfo(f32).eps
        myacc += (s12 * s12) / den;
    }

    __shared__ float red[256];
    red[threadIdx.x] = myacc;
    __syncthreads();
    #pragma unroll
    for (int s = 128; s > 0; s >>= 1) {
        if (threadIdx.x < s) red[threadIdx.x] += red[threadIdx.x + s];
        __syncthreads();
    }
    if (threadIdx.x == 0) atomicAdd(acc, (double)red[0]);
}

// ---------------------------------------------------------------------------
__global__ void k_fin(const double* __restrict__ acc, float* __restrict__ out) {
    out[0] = (float)(-(*acc) / (double)N_);
}

// ---------------------------------------------------------------------------
extern "C" void kernel_launch(void* const* d_in, const int* in_sizes, int n_in,
                              void* d_out, int out_size, void* d_ws, size_t ws_size,
                              hipStream_t stream) {
    const float* pred = (const float*)d_in[0];
    const float* targ = (const float*)d_in[1];

    uint4*  buf = (uint4*)d_ws;                                   // N_ x 16B
    double* acc = (double*)((char*)d_ws + (size_t)N_ * 16);       // 8B aligned
    float*  out = (float*)d_out;

    k_init<<<1, 1, 0, stream>>>(acc);
    dim3 g1(D_, NSEG);          // 160 x 24
    k_passWH<<<g1, 128, 0, stream>>>(pred, targ, buf);
    dim3 g3(HW_ / 256, 8);      // 168 x 8
    k_passD<<<g3, 256, 0, stream>>>(buf, acc);
    k_fin<<<1, 1, 0, stream>>>(acc, out);
}

// Round 7
// 78.633 us; speedup vs baseline: 1.2645x; 1.0478x over previous
//
#include <hip/hip_runtime.h>
#include <hip/hip_fp16.h>

#define D_  160
#define H_  192
#define W_  224
#define HW_ (H_ * W_)           // 43008
#define N_  (D_ * H_ * W_)      // 6881280
#define INV729 (1.0f / 729.0f)
#define HSEG 8
#define NSEG (H_ / HSEG)        // 24
#define NSTEP (HSEG + 9)        // 17

// LDS anti-conflict index padding: one spare dword per 32. PI(even i)+1 ==
// PI(i+1), so float2-shaped reads stay mergeable into ds_read2_b32.
__device__ __forceinline__ int PI(int i) { return i + (i >> 5); }

// Intermediate: bufA = uint4 per 2 points (c0..c3 of pt0, c0..c3 of pt1, fp16)
//               bufB = ushort per point (c4, fp16)

// ---------------------------------------------------------------------------
__global__ void k_init(double* acc) { *acc = 0.0; }

__device__ __forceinline__ unsigned pack2(float a, float b) {
    const __half2 h = __floats2half2_rn(a, b);
    return *(const unsigned*)&h;
}

// ---------------------------------------------------------------------------
// Fused W+H box-sum, 2 w-points/thread, fp16 H-ring, split fp16 output.
__global__ __launch_bounds__(128) void k_passWH(const float* __restrict__ pred,
                                                const float* __restrict__ targ,
                                                uint4* __restrict__ outA,   // [N/2]
                                                unsigned* __restrict__ outB) { // [N/2]
    __shared__ __attribute__((aligned(16))) float bI[2][240];
    __shared__ __attribute__((aligned(16))) float bJ[2][240];
    const int d  = blockIdx.x;
    const int h0 = blockIdx.y * HSEG;
    const int t  = threadIdx.x;
    const long dbase = (long)d * HW_;

    // staging role: t<116 -> array sa (0=I=targ,1=J=pred), chunk sc (0..57)
    // chunk sc covers logical LDS slots [4sc,4sc+3] = w elements [4sc-4,4sc-1]
    const bool stg = (t < 116);
    const int  sa  = (t >= 58) ? 1 : 0;
    const int  sc  = sa ? (t - 58) : t;
    const bool interior = (sc >= 1) && (sc <= 56);   // chunks 0,57 = zero halo
    const float* src = sa ? pred : targ;
    const long srcoff = dbase + (long)(4 * sc - 4);

    const bool cmp = (t < 112);      // owns w = {2t, 2t+1}
    const int  l   = t;

    __half2 q[5][9];
    #pragma unroll
    for (int c = 0; c < 5; ++c)
        #pragma unroll
        for (int k = 0; k < 9; ++k) q[c][k] = __floats2half2_rn(0.f, 0.f);
    float S0[5] = {0,0,0,0,0}, S1[5] = {0,0,0,0,0};

    float4 pf = make_float4(0.f, 0.f, 0.f, 0.f);
    {
        const int hh = h0 - 5;
        if (stg && interior && hh >= 0)
            pf = *(const float4*)(src + srcoff + (long)hh * W_);
    }

    #pragma unroll
    for (int k = 0; k < NSTEP; ++k) {
        const int cur = k & 1;
        if (stg) {
            float* dst = sa ? bJ[cur] : bI[cur];
            const int p0 = PI(4 * sc);   // 4sc..4sc+3 stay contiguous after PI
            dst[p0]     = pf.x;
            dst[p0 + 1] = pf.y;
            dst[p0 + 2] = pf.z;
            dst[p0 + 3] = pf.w;
        }
        pf = make_float4(0.f, 0.f, 0.f, 0.f);
        {
            const int hh = h0 - 4 + k;
            if (stg && interior && (k + 1 < NSTEP) && hh >= 0 && hh < H_)
                pf = *(const float4*)(src + srcoff + (long)hh * W_);
        }
        __syncthreads();
        // hazard: reads of buf[cur] precede barrier(k+1); next write to
        // buf[cur] is in step k+2 after barrier(k+1). OK.

        if (cmp) {
            // window: w elements 2l-4 .. 2l+5 = logical slots 2l .. 2l+9
            float a[10], b[10];
            #pragma unroll
            for (int m = 0; m < 5; ++m) {
                const int p0 = PI(2 * l + 2 * m);    // p0+1 == PI(2l+2m+1)
                a[2*m] = bI[cur][p0]; a[2*m+1] = bI[cur][p0 + 1];
                b[2*m] = bJ[cur][p0]; b[2*m+1] = bJ[cur][p0 + 1];
            }
            float sI = 0.f, sJ = 0.f, sII = 0.f, sJJ = 0.f, sIJ = 0.f;
            #pragma unroll
            for (int kk = 0; kk < 9; ++kk) {
                sI  += a[kk];          sJ  += b[kk];
                sII += a[kk] * a[kk];  sJJ += b[kk] * b[kk];
                sIJ += a[kk] * b[kk];
            }
            float w0[5], w1[5];
            w0[0] = sI;  w1[0] = sI  + a[9] - a[0];
            w0[1] = sJ;  w1[1] = sJ  + b[9] - b[0];
            w0[2] = sII; w1[2] = sII + a[9]*a[9] - a[0]*a[0];
            w0[3] = sJJ; w1[3] = sJJ + b[9]*b[9] - b[0]*b[0];
            w0[4] = sIJ; w1[4] = sIJ + a[9]*b[9] - a[0]*b[0];

            const int p = k % 9;      // compile-time (full unroll)
            #pragma unroll
            for (int c = 0; c < 5; ++c) {
                const __half2 nq = __floats2half2_rn(w0[c], w1[c]);
                const float2  nf = __half22float2(nq);
                const float2  of = __half22float2(q[c][p]);
                S0[c] += nf.x - of.x;
                S1[c] += nf.y - of.y;
                q[c][p] = nq;
            }
            if (k >= 9) {
                const long rb = dbase + (long)(h0 + k - 9) * W_;   // even
                uint4 oA;
                oA.x = pack2(S0[0], S0[1]); oA.y = pack2(S0[2], S0[3]);
                oA.z = pack2(S1[0], S1[1]); oA.w = pack2(S1[2], S1[3]);
                outA[rb / 2 + l] = oA;
                outB[rb / 2 + l] = pack2(S0[4], S1[4]);
            }
        }
    }
}

// ---------------------------------------------------------------------------
// D-axis 9-tap sliding sum + cc + reduction. Per point-step: one dwordx2
// (c0..c3) + one ushort (c4). R2-proven loop structure.
__global__ __launch_bounds__(256) void k_passD(const uint2* __restrict__ bufA,
                                               const unsigned short* __restrict__ bufB,
                                               double* __restrict__ acc) {
    const int DSEG = D_ / 8;                // 20
    const int p  = blockIdx.x * blockDim.x + threadIdx.x;   // < HW_
    const int d0 = blockIdx.y * DSEG;

    float q[5][9], S[5];
    #pragma unroll
    for (int c = 0; c < 5; ++c) S[c] = 0.f;

    #pragma unroll
    for (int k = 0; k < 9; ++k) {
        const int dd = d0 - 5 + k;          // d0+3 <= 143 < 160
        uint2 va = make_uint2(0u, 0u);
        unsigned short vb = 0;
        if (dd >= 0) {
            va = bufA[(long)dd * HW_ + p];
            vb = bufB[(long)dd * HW_ + p];
        }
        const float2 f01 = __half22float2(*(const __half2*)&va.x);
        const float2 f23 = __half22float2(*(const __half2*)&va.y);
        const float  f4  = __half2float(*(const __half*)&vb);
        q[0][k] = f01.x; S[0] += f01.x;
        q[1][k] = f01.y; S[1] += f01.y;
        q[2][k] = f23.x; S[2] += f23.x;
        q[3][k] = f23.y; S[3] += f23.y;
        q[4][k] = f4;    S[4] += f4;
    }

    float myacc = 0.f;
    #pragma unroll 2
    for (int d = d0; d < d0 + DSEG; ++d) {
        uint2 va = make_uint2(0u, 0u);
        unsigned short vb = 0;
        if (d + 4 < D_) {
            va = bufA[(long)(d + 4) * HW_ + p];
            vb = bufB[(long)(d + 4) * HW_ + p];
        }
        const float2 f01 = __half22float2(*(const __half2*)&va.x);
        const float2 f23 = __half22float2(*(const __half2*)&va.y);
        const float  f4  = __half2float(*(const __half*)&vb);
        float nv[5] = {f01.x, f01.y, f23.x, f23.y, f4};
        #pragma unroll
        for (int c = 0; c < 5; ++c) {
            S[c] += nv[c] - q[c][0];
            #pragma unroll
            for (int k = 0; k < 8; ++k) q[c][k] = q[c][k + 1];
            q[c][8] = nv[c];
        }
        const float mu1 = S[0] * INV729;
        const float mu2 = S[1] * INV729;
        const float s1  = S[2] * INV729 - mu1 * mu1;
        const float s2  = S[3] * INV729 - mu2 * mu2;
        const float s12 = S[4] * INV729 - mu1 * mu2;
        const float den = fmaxf(s1 * s2, 1.1920929e-7f);   // finfo(f32).eps
        myacc += (s12 * s12) / den;
    }

    __shared__ float red[256];
    red[threadIdx.x] = myacc;
    __syncthreads();
    #pragma unroll
    for (int s = 128; s > 0; s >>= 1) {
        if (threadIdx.x < s) red[threadIdx.x] += red[threadIdx.x + s];
        __syncthreads();
    }
    if (threadIdx.x == 0) atomicAdd(acc, (double)red[0]);
}

// ---------------------------------------------------------------------------
__global__ void k_fin(const double* __restrict__ acc, float* __restrict__ out) {
    out[0] = (float)(-(*acc) / (double)N_);
}

// ---------------------------------------------------------------------------
extern "C" void kernel_launch(void* const* d_in, const int* in_sizes, int n_in,
                              void* d_out, int out_size, void* d_ws, size_t ws_size,
                              hipStream_t stream) {
    const float* pred = (const float*)d_in[0];
    const float* targ = (const float*)d_in[1];

    uint4*    bufA = (uint4*)d_ws;                                 // N/2 x 16B = 55 MB
    unsigned* bufB = (unsigned*)((char*)d_ws + (size_t)(N_ / 2) * 16);  // N x 2B = 13.8 MB
    double*   acc  = (double*)((char*)d_ws + (size_t)(N_ / 2) * 16 + (size_t)N_ * 2);
    float*    out  = (float*)d_out;

    k_init<<<1, 1, 0, stream>>>(acc);
    dim3 g1(D_, NSEG);          // 160 x 24
    k_passWH<<<g1, 128, 0, stream>>>(pred, targ, bufA, (unsigned*)bufB);
    dim3 g3(HW_ / 256, 8);      // 168 x 8
    k_passD<<<g3, 256, 0, stream>>>((const uint2*)bufA, (const unsigned short*)bufB, acc);
    k_fin<<<1, 1, 0, stream>>>(acc, out);
}

// Round 8
// 73.884 us; speedup vs baseline: 1.3457x; 1.0643x over previous
//
#include <hip/hip_runtime.h>
#include <hip/hip_fp16.h>

#define D_  160
#define H_  192
#define W_  224
#define HW_ (H_ * W_)           // 43008
#define N_  (D_ * H_ * W_)      // 6881280
#define INV729 (1.0f / 729.0f)
#define HSEG 12
#define NSEG (H_ / HSEG)        // 16
#define NSTEP (HSEG + 9)        // 21

// LDS anti-conflict index padding: TWO spare dwords per 32 (b64 reads: lane
// t+16 lands 2 banks after lane t's pair -> no pair overlap).
// PI(even)+1 == PI(even+1) and 4sc..4sc+3 stay contiguous (groups of 32).
__device__ __forceinline__ int PI(int i) { return i + ((i >> 5) << 1); }

// Intermediate: bufA = uint4 per 2 points (c0..c3 pt0, c0..c3 pt1, fp16)
//               bufB = dword per 2 points (c4 pt0, c4 pt1, fp16)

// ---------------------------------------------------------------------------
__global__ void k_init(double* acc) { *acc = 0.0; }

__device__ __forceinline__ unsigned pack2(float a, float b) {
    const __half2 h = __floats2half2_rn(a, b);
    return *(const unsigned*)&h;
}

// ---------------------------------------------------------------------------
// Fused W+H box-sum, 2 w-points/thread, fp32 H-ring, split fp16 output.
__global__ __launch_bounds__(128) void k_passWH(const float* __restrict__ pred,
                                                const float* __restrict__ targ,
                                                uint4* __restrict__ outA,     // [N/2]
                                                unsigned* __restrict__ outB) { // [N/2]
    __shared__ __attribute__((aligned(16))) float bI[2][248];
    __shared__ __attribute__((aligned(16))) float bJ[2][248];
    const int d  = blockIdx.x;
    const int h0 = blockIdx.y * HSEG;
    const int t  = threadIdx.x;
    const long dbase = (long)d * HW_;

    // staging role: t<116 -> array sa (0=I=targ,1=J=pred), chunk sc (0..57)
    // chunk sc covers logical LDS slots [4sc,4sc+3] = w elements [4sc-4,4sc-1]
    const bool stg = (t < 116);
    const int  sa  = (t >= 58) ? 1 : 0;
    const int  sc  = sa ? (t - 58) : t;
    const bool interior = (sc >= 1) && (sc <= 56);   // chunks 0,57 = zero halo
    const float* src = sa ? pred : targ;
    const long srcoff = dbase + (long)(4 * sc - 4);

    const bool cmp = (t < 112);      // owns w = {2t, 2t+1}
    const int  l   = t;

    // fp32 H-ring: q[c][p] = (w-sum for pt0, pt1) of row pushed at phase p
    float2 q[5][9];
    #pragma unroll
    for (int c = 0; c < 5; ++c)
        #pragma unroll
        for (int k = 0; k < 9; ++k) q[c][k] = make_float2(0.f, 0.f);
    float S0[5] = {0,0,0,0,0}, S1[5] = {0,0,0,0,0};

    float4 pf = make_float4(0.f, 0.f, 0.f, 0.f);
    {
        const int hh = h0 - 5;
        if (stg && interior && hh >= 0)
            pf = *(const float4*)(src + srcoff + (long)hh * W_);
    }

    #pragma unroll
    for (int k = 0; k < NSTEP; ++k) {
        const int cur = k & 1;
        if (stg) {
            float* dst = sa ? bJ[cur] : bI[cur];
            const int p0 = PI(4 * sc);   // 4 contiguous slots after PI
            dst[p0]     = pf.x;
            dst[p0 + 1] = pf.y;
            dst[p0 + 2] = pf.z;
            dst[p0 + 3] = pf.w;
        }
        pf = make_float4(0.f, 0.f, 0.f, 0.f);
        {
            const int hh = h0 - 4 + k;
            if (stg && interior && (k + 1 < NSTEP) && hh >= 0 && hh < H_)
                pf = *(const float4*)(src + srcoff + (long)hh * W_);
        }
        __syncthreads();
        // hazard: reads of buf[cur] precede barrier(k+1); next write to
        // buf[cur] is in step k+2 after barrier(k+1). OK.

        if (cmp) {
            // window: w elements 2l-4 .. 2l+5 = logical slots 2l .. 2l+9
            float a[10], b[10];
            #pragma unroll
            for (int m = 0; m < 5; ++m) {
                const int p0 = PI(2 * l + 2 * m);    // p0+1 == PI(2l+2m+1)
                a[2*m] = bI[cur][p0]; a[2*m+1] = bI[cur][p0 + 1];
                b[2*m] = bJ[cur][p0]; b[2*m+1] = bJ[cur][p0 + 1];
            }
            float sI = 0.f, sJ = 0.f, sII = 0.f, sJJ = 0.f, sIJ = 0.f;
            #pragma unroll
            for (int kk = 0; kk < 9; ++kk) {
                sI  += a[kk];          sJ  += b[kk];
                sII += a[kk] * a[kk];  sJJ += b[kk] * b[kk];
                sIJ += a[kk] * b[kk];
            }
            float w0[5], w1[5];
            w0[0] = sI;  w1[0] = sI  + a[9] - a[0];
            w0[1] = sJ;  w1[1] = sJ  + b[9] - b[0];
            w0[2] = sII; w1[2] = sII + a[9]*a[9] - a[0]*a[0];
            w0[3] = sJJ; w1[3] = sJJ + b[9]*b[9] - b[0]*b[0];
            w0[4] = sIJ; w1[4] = sIJ + a[9]*b[9] - a[0]*b[0];

            const int p = k % 9;      // compile-time (full unroll)
            #pragma unroll
            for (int c = 0; c < 5; ++c) {
                S0[c] += w0[c] - q[c][p].x;
                S1[c] += w1[c] - q[c][p].y;
                q[c][p].x = w0[c];
                q[c][p].y = w1[c];
            }
            if (k >= 9) {
                const long rb = dbase + (long)(h0 + k - 9) * W_;   // even
                uint4 oA;
                oA.x = pack2(S0[0], S0[1]); oA.y = pack2(S0[2], S0[3]);
                oA.z = pack2(S1[0], S1[1]); oA.w = pack2(S1[2], S1[3]);
                outA[rb / 2 + l] = oA;
                outB[rb / 2 + l] = pack2(S0[4], S1[4]);
            }
        }
    }
}

// ---------------------------------------------------------------------------
// D-axis 9-tap sliding sum + cc + reduction. Per point-step: one dwordx2
// (c0..c3) + one ushort (c4). R2-proven loop structure. (unchanged from R7)
__global__ __launch_bounds__(256) void k_passD(const uint2* __restrict__ bufA,
                                               const unsigned short* __restrict__ bufB,
                                               double* __restrict__ acc) {
    const int DSEG = D_ / 8;                // 20
    const int p  = blockIdx.x * blockDim.x + threadIdx.x;   // < HW_
    const int d0 = blockIdx.y * DSEG;

    float q[5][9], S[5];
    #pragma unroll
    for (int c = 0; c < 5; ++c) S[c] = 0.f;

    #pragma unroll
    for (int k = 0; k < 9; ++k) {
        const int dd = d0 - 5 + k;          // d0+3 <= 143 < 160
        uint2 va = make_uint2(0u, 0u);
        unsigned short vb = 0;
        if (dd >= 0) {
            va = bufA[(long)dd * HW_ + p];
            vb = bufB[(long)dd * HW_ + p];
        }
        const float2 f01 = __half22float2(*(const __half2*)&va.x);
        const float2 f23 = __half22float2(*(const __half2*)&va.y);
        const float  f4  = __half2float(*(const __half*)&vb);
        q[0][k] = f01.x; S[0] += f01.x;
        q[1][k] = f01.y; S[1] += f01.y;
        q[2][k] = f23.x; S[2] += f23.x;
        q[3][k] = f23.y; S[3] += f23.y;
        q[4][k] = f4;    S[4] += f4;
    }

    float myacc = 0.f;
    #pragma unroll 2
    for (int d = d0; d < d0 + DSEG; ++d) {
        uint2 va = make_uint2(0u, 0u);
        unsigned short vb = 0;
        if (d + 4 < D_) {
            va = bufA[(long)(d + 4) * HW_ + p];
            vb = bufB[(long)(d + 4) * HW_ + p];
        }
        const float2 f01 = __half22float2(*(const __half2*)&va.x);
        const float2 f23 = __half22float2(*(const __half2*)&va.y);
        const float  f4  = __half2float(*(const __half*)&vb);
        float nv[5] = {f01.x, f01.y, f23.x, f23.y, f4};
        #pragma unroll
        for (int c = 0; c < 5; ++c) {
            S[c] += nv[c] - q[c][0];
            #pragma unroll
            for (int k = 0; k < 8; ++k) q[c][k] = q[c][k + 1];
            q[c][8] = nv[c];
        }
        const float mu1 = S[0] * INV729;
        const float mu2 = S[1] * INV729;
        const float s1  = S[2] * INV729 - mu1 * mu1;
        const float s2  = S[3] * INV729 - mu2 * mu2;
        const float s12 = S[4] * INV729 - mu1 * mu2;
        const float den = fmaxf(s1 * s2, 1.1920929e-7f);   // finfo(f32).eps
        myacc += (s12 * s12) / den;
    }

    __shared__ float red[256];
    red[threadIdx.x] = myacc;
    __syncthreads();
    #pragma unroll
    for (int s = 128; s > 0; s >>= 1) {
        if (threadIdx.x < s) red[threadIdx.x] += red[threadIdx.x + s];
        __syncthreads();
    }
    if (threadIdx.x == 0) atomicAdd(acc, (double)red[0]);
}

// ---------------------------------------------------------------------------
__global__ void k_fin(const double* __restrict__ acc, float* __restrict__ out) {
    out[0] = (float)(-(*acc) / (double)N_);
}

// ---------------------------------------------------------------------------
extern "C" void kernel_launch(void* const* d_in, const int* in_sizes, int n_in,
                              void* d_out, int out_size, void* d_ws, size_t ws_size,
                              hipStream_t stream) {
    const float* pred = (const float*)d_in[0];
    const float* targ = (const float*)d_in[1];

    uint4*    bufA = (uint4*)d_ws;                                 // N/2 x 16B = 55 MB
    unsigned* bufB = (unsigned*)((char*)d_ws + (size_t)(N_ / 2) * 16);  // N x 2B = 13.8 MB
    double*   acc  = (double*)((char*)d_ws + (size_t)(N_ / 2) * 16 + (size_t)N_ * 2);
    float*    out  = (float*)d_out;

    k_init<<<1, 1, 0, stream>>>(acc);
    dim3 g1(D_, NSEG);          // 160 x 16 = 2560 blocks (10/CU exactly)
    k_passWH<<<g1, 128, 0, stream>>>(pred, targ, bufA, (unsigned*)bufB);
    dim3 g3(HW_ / 256, 8);      // 168 x 8
    k_passD<<<g3, 256, 0, stream>>>((const uint2*)bufA, (const unsigned short*)bufB, acc);
    k_fin<<<1, 1, 0, stream>>>(acc, out);
}

// Round 9
// 64.794 us; speedup vs baseline: 1.5345x; 1.1403x over previous
//
#include <hip/hip_runtime.h>
#include <hip/hip_fp16.h>

#define D_  160
#define H_  192
#define W_  224
#define HW_ (H_ * W_)           // 43008
#define HW2_ (HW_ / 2)          // 21504
#define N_  (D_ * H_ * W_)      // 6881280
#define INV729 (1.0f / 729.0f)
#define HSEG 16
#define NSEG (H_ / HSEG)        // 12
#define NSTEP2 13               // 2-row steps: pushes p=0..25 (25 unused-emit)

// LDS index pad: FOUR spare dwords per 32 -> PI4(4sc) stays mult-of-4 (b128
// aligned writes); even-pair reads stay contiguous (no group crossing).
__device__ __forceinline__ int PI4(int i) { return i + ((i >> 5) << 2); }

// Intermediate: bufA = uint4 per 2 points (c0..c3 pt0, c0..c3 pt1, fp16)
//               bufB = dword per 2 points (c4 pt0, c4 pt1, fp16)

// ---------------------------------------------------------------------------
__global__ void k_init(double* acc) { *acc = 0.0; }

__device__ __forceinline__ unsigned pack2(float a, float b) {
    const __half2 h = __floats2half2_rn(a, b);
    return *(const unsigned*)&h;
}

// ---------------------------------------------------------------------------
// Fused W+H box-sum. 2 w-points/thread, fp32 H-ring, TWO rows per barrier.
__global__ __launch_bounds__(128) void k_passWH(const float* __restrict__ pred,
                                                const float* __restrict__ targ,
                                                uint4* __restrict__ outA,      // [N/2]
                                                unsigned* __restrict__ outB) { // [N/2]
    __shared__ __attribute__((aligned(16))) float bI[2][2][264]; // [buf][row][slot]
    __shared__ __attribute__((aligned(16))) float bJ[2][2][264];
    const int d  = blockIdx.x;
    const int h0 = blockIdx.y * HSEG;
    const int t  = threadIdx.x;
    const long dbase = (long)d * HW_;

    // staging role: t<116 -> array sa (0=I=targ,1=J=pred), chunk sc (0..57)
    // chunk sc covers logical slots [4sc,4sc+3] = w elements [4sc-4,4sc-1]
    const bool stg = (t < 116);
    const int  sa  = (t >= 58) ? 1 : 0;
    const int  sc  = sa ? (t - 58) : t;
    const bool interior = (sc >= 1) && (sc <= 56);   // chunks 0,57 = zero halo
    const float* src = sa ? pred : targ;
    const long srcoff = dbase + (long)(4 * sc - 4);

    const bool cmp = (t < 112);      // owns w = {2t, 2t+1}
    const int  l   = t;

    // fp32 H-ring: q[c][p%9] = (w-sum pt0, pt1) of push-index p
    float2 q[5][9];
    #pragma unroll
    for (int c = 0; c < 5; ++c)
        #pragma unroll
        for (int k = 0; k < 9; ++k) q[c][k] = make_float2(0.f, 0.f);
    float S0[5] = {0,0,0,0,0}, S1[5] = {0,0,0,0,0};

    float4 pf0 = make_float4(0.f,0.f,0.f,0.f), pf1 = pf0;
    auto fetch = [&](int p, float4& f) {
        f = make_float4(0.f, 0.f, 0.f, 0.f);
        const int hh = h0 - 5 + p;
        if (stg && interior && p < 26 && hh >= 0 && hh < H_)
            f = *(const float4*)(src + srcoff + (long)hh * W_);
    };
    fetch(0, pf0);
    fetch(1, pf1);

    #pragma unroll
    for (int k = 0; k < NSTEP2; ++k) {
        const int cur = k & 1;
        if (stg) {
            float* base = sa ? &bJ[cur][0][0] : &bI[cur][0][0];
            const int p0 = PI4(4 * sc);          // mult of 4 -> 16B aligned
            *(float4*)(base + p0)       = pf0;   // row 0
            *(float4*)(base + 264 + p0) = pf1;   // row 1
        }
        fetch(2 * k + 2, pf0);                   // prefetch next step's rows
        fetch(2 * k + 3, pf1);
        __syncthreads();
        // hazard: reads of buf[cur] precede barrier(k+1); next write to
        // buf[cur] is step k+2 after barrier(k+1). OK.

        if (cmp) {
            #pragma unroll
            for (int r = 0; r < 2; ++r) {
                const int p = 2 * k + r;         // compile-time
                // window: slots 2l .. 2l+9
                float a[10], b[10];
                #pragma unroll
                for (int m = 0; m < 5; ++m) {
                    const int pp = PI4(2 * l + 2 * m);   // pp+1 = next slot
                    a[2*m] = bI[cur][r][pp]; a[2*m+1] = bI[cur][r][pp + 1];
                    b[2*m] = bJ[cur][r][pp]; b[2*m+1] = bJ[cur][r][pp + 1];
                }
                float sI = 0.f, sJ = 0.f, sII = 0.f, sJJ = 0.f, sIJ = 0.f;
                #pragma unroll
                for (int kk = 0; kk < 9; ++kk) {
                    sI  += a[kk];          sJ  += b[kk];
                    sII += a[kk] * a[kk];  sJJ += b[kk] * b[kk];
                    sIJ += a[kk] * b[kk];
                }
                float w0[5], w1[5];
                w0[0] = sI;  w1[0] = sI  + a[9] - a[0];
                w0[1] = sJ;  w1[1] = sJ  + b[9] - b[0];
                w0[2] = sII; w1[2] = sII + a[9]*a[9] - a[0]*a[0];
                w0[3] = sJJ; w1[3] = sJJ + b[9]*b[9] - b[0]*b[0];
                w0[4] = sIJ; w1[4] = sIJ + a[9]*b[9] - a[0]*b[0];

                const int ph = p % 9;            // compile-time
                #pragma unroll
                for (int c = 0; c < 5; ++c) {
                    S0[c] += w0[c] - q[c][ph].x;
                    S1[c] += w1[c] - q[c][ph].y;
                    q[c][ph].x = w0[c];
                    q[c][ph].y = w1[c];
                }
                if (p >= 9 && (p - 9) < HSEG) {  // emit row h0+p-9
                    const long rb = dbase + (long)(h0 + p - 9) * W_;  // even
                    uint4 oA;
                    oA.x = pack2(S0[0], S0[1]); oA.y = pack2(S0[2], S0[3]);
                    oA.z = pack2(S1[0], S1[1]); oA.w = pack2(S1[2], S1[3]);
                    outA[rb / 2 + l] = oA;
                    outB[rb / 2 + l] = pack2(S0[4], S1[4]);
                }
            }
        }
    }
}

// ---------------------------------------------------------------------------
// D-axis 9-tap sliding sum + cc + reduction. TWO points per thread: one b128
// (bufA: c0..c3 of both pts) + one b32 (bufB: c4 of both pts) per d-step.
__global__ __launch_bounds__(256) void k_passD(const uint4* __restrict__ bufA,
                                               const unsigned* __restrict__ bufB,
                                               double* __restrict__ acc) {
    const int DSEG = D_ / 8;                // 20
    const int p2 = blockIdx.x * blockDim.x + threadIdx.x;   // < HW2_
    const int d0 = blockIdx.y * DSEG;

    float2 q[5][9], S[5];                   // .x = pt0, .y = pt1
    #pragma unroll
    for (int c = 0; c < 5; ++c) S[c] = make_float2(0.f, 0.f);

    #pragma unroll
    for (int k = 0; k < 9; ++k) {
        const int dd = d0 - 5 + k;          // d0+3 <= 143 < 160
        uint4 va = make_uint4(0u, 0u, 0u, 0u);
        unsigned vb = 0u;
        if (dd >= 0) {
            va = bufA[(long)dd * HW2_ + p2];
            vb = bufB[(long)dd * HW2_ + p2];
        }
        const float2 a01 = __half22float2(*(const __half2*)&va.x);  // pt0 c0,c1
        const float2 a23 = __half22float2(*(const __half2*)&va.y);  // pt0 c2,c3
        const float2 b01 = __half22float2(*(const __half2*)&va.z);  // pt1 c0,c1
        const float2 b23 = __half22float2(*(const __half2*)&va.w);  // pt1 c2,c3
        const float2 c44 = __half22float2(*(const __half2*)&vb);    // c4 pt0,pt1
        q[0][k] = make_float2(a01.x, b01.x); S[0].x += a01.x; S[0].y += b01.x;
        q[1][k] = make_float2(a01.y, b01.y); S[1].x += a01.y; S[1].y += b01.y;
        q[2][k] = make_float2(a23.x, b23.x); S[2].x += a23.x; S[2].y += b23.x;
        q[3][k] = make_float2(a23.y, b23.y); S[3].x += a23.y; S[3].y += b23.y;
        q[4][k] = make_float2(c44.x, c44.y); S[4].x += c44.x; S[4].y += c44.y;
    }

    float myacc = 0.f;
    #pragma unroll
    for (int j = 0; j < DSEG; ++j) {        // output d = d0+j
        const int dd = d0 + 4 + j;
        uint4 va = make_uint4(0u, 0u, 0u, 0u);
        unsigned vb = 0u;
        if (dd < D_) {
            va = bufA[(long)dd * HW2_ + p2];
            vb = bufB[(long)dd * HW2_ + p2];
        }
        const float2 a01 = __half22float2(*(const __half2*)&va.x);
        const float2 a23 = __half22float2(*(const __half2*)&va.y);
        const float2 b01 = __half22float2(*(const __half2*)&va.z);
        const float2 b23 = __half22float2(*(const __half2*)&va.w);
        const float2 c44 = __half22float2(*(const __half2*)&vb);
        const float2 nv[5] = {
            make_float2(a01.x, b01.x), make_float2(a01.y, b01.y),
            make_float2(a23.x, b23.x), make_float2(a23.y, b23.y),
            make_float2(c44.x, c44.y)
        };
        const int ph = j % 9;               // compile-time
        #pragma unroll
        for (int c = 0; c < 5; ++c) {
            S[c].x += nv[c].x - q[c][ph].x;
            S[c].y += nv[c].y - q[c][ph].y;
            q[c][ph] = nv[c];
        }
        #pragma unroll
        for (int e = 0; e < 2; ++e) {
            const float mu1 = (e ? S[0].y : S[0].x) * INV729;
            const float mu2 = (e ? S[1].y : S[1].x) * INV729;
            const float s1  = (e ? S[2].y : S[2].x) * INV729 - mu1 * mu1;
            const float s2  = (e ? S[3].y : S[3].x) * INV729 - mu2 * mu2;
            const float s12 = (e ? S[4].y : S[4].x) * INV729 - mu1 * mu2;
            const float den = fmaxf(s1 * s2, 1.1920929e-7f);  // finfo(f32).eps
            myacc += (s12 * s12) / den;
        }
    }

    __shared__ float red[256];
    red[threadIdx.x] = myacc;
    __syncthreads();
    #pragma unroll
    for (int s = 128; s > 0; s >>= 1) {
        if (threadIdx.x < s) red[threadIdx.x] += red[threadIdx.x + s];
        __syncthreads();
    }
    if (threadIdx.x == 0) atomicAdd(acc, (double)red[0]);
}

// ---------------------------------------------------------------------------
__global__ void k_fin(const double* __restrict__ acc, float* __restrict__ out) {
    out[0] = (float)(-(*acc) / (double)N_);
}

// ---------------------------------------------------------------------------
extern "C" void kernel_launch(void* const* d_in, const int* in_sizes, int n_in,
                              void* d_out, int out_size, void* d_ws, size_t ws_size,
                              hipStream_t stream) {
    const float* pred = (const float*)d_in[0];
    const float* targ = (const float*)d_in[1];

    uint4*    bufA = (uint4*)d_ws;                                 // N/2 x 16B = 55 MB
    unsigned* bufB = (unsigned*)((char*)d_ws + (size_t)(N_ / 2) * 16);  // N/2 x 4B
    double*   acc  = (double*)((char*)d_ws + (size_t)(N_ / 2) * 16 + (size_t)(N_ / 2) * 4);
    float*    out  = (float*)d_out;

    k_init<<<1, 1, 0, stream>>>(acc);
    dim3 g1(D_, NSEG);          // 160 x 12 = 1920 blocks
    k_passWH<<<g1, 128, 0, stream>>>(pred, targ, bufA, bufB);
    dim3 g3(HW2_ / 256, 8);     // 84 x 8 = 672 blocks
    k_passD<<<g3, 256, 0, stream>>>(bufA, bufB, acc);
    k_fin<<<1, 1, 0, stream>>>(acc, out);
}